// Round 4
// baseline (272.496 us; speedup 1.0000x reference)
//
#include <hip/hip_runtime.h>
#include <math.h>

#define NTOK 16384
#define DDIM 2048
#define NEXP 64
#define MT   128                 // tokens per stage-1 block
#define KSPLIT 8
#define KRANGE (DDIM / KSPLIT)   // 256
#define KC   32                  // k per LDS chunk
#define NCH  (KRANGE / KC)       // 8

// ws layout (floats): [0..63] f counts, [64..127] P sums, [128] sum lse^2,
// [256 ...] partial logits: [KSPLIT][NTOK][NEXP]
#define PART_OFF 256

// x-tile LDS index with ty-spreading XOR swizzle (float-index domain).
// row in [0,128), kf in [0,32). XOR by ((row>>3)&3)*4 floats spreads the 4
// ty-groups (row bits 3..4) across 4 bank quadrants; float4/float2 alignment
// is preserved (XOR operand is a multiple of 4 / within-16B granule).
#define XSWZ(row, kf) ((((row) * KC) + (kf)) ^ ((((row) >> 3) & 3) * 4))

__global__ void zero_acc(float* acc) {
    int t = threadIdx.x;
    if (t < 129) acc[t] = 0.0f;
}

__global__ __launch_bounds__(256, 4) void gemm_part(
    const float* __restrict__ x, const float* __restrict__ W,
    float* __restrict__ pws)
{
    __shared__ __align__(16) float xs[MT * KC];     // 128 tok x 32 k, swizzled
    __shared__ __align__(16) float wsm[KC * NEXP];  // 32 k x 64 experts, linear

    const int tid  = threadIdx.x;
    const int tb   = blockIdx.x & (NTOK / MT - 1);  // token block 0..127
    const int s    = blockIdx.x >> 7;               // k-split 0..7
    const int tok0 = tb * MT;
    const int kb   = s * KRANGE;

    const int tx = tid & 15;             // experts 4tx..4tx+3
    const int ty = tid >> 4;             // tokens 8ty..8ty+7
    const int e0 = tx * 4;

    // x staging: 4 float4/thread; f4 index u*256+tid -> row=idx>>3, c4=idx&7
    const int xr0 = tid >> 3;            // rows 0..31 (u adds 32)
    const int xc0 = (tid & 7) * 4;       // float col within 32-k chunk
    // W staging: 2 float4/thread; f4 index u*256+tid -> row=idx>>4, c4=idx&15
    const int wr0 = tid >> 4;            // rows 0..15 (u adds 16)
    const int wc0 = (tid & 15) * 4;

    const float* xg = x + (size_t)(tok0 + xr0) * DDIM + kb + xc0;
    const float* wg = W + (size_t)(kb + wr0) * NEXP + wc0;

    float4 px[4], pw[2];
    #pragma unroll
    for (int u = 0; u < 4; ++u)
        px[u] = *(const float4*)(xg + (size_t)u * 32 * DDIM);
    #pragma unroll
    for (int u = 0; u < 2; ++u)
        pw[u] = *(const float4*)(wg + (size_t)u * 16 * NEXP);

    float acc[8][4];
    #pragma unroll
    for (int t = 0; t < 8; ++t)
        #pragma unroll
        for (int j = 0; j < 4; ++j) acc[t][j] = 0.0f;

    for (int c = 0; c < NCH; ++c) {
        __syncthreads();   // previous chunk's LDS reads done
        #pragma unroll
        for (int u = 0; u < 4; ++u)
            *(float4*)&xs[XSWZ(xr0 + u * 32, xc0)] = px[u];
        #pragma unroll
        for (int u = 0; u < 2; ++u)
            *(float4*)&wsm[(wr0 + u * 16) * NEXP + wc0] = pw[u];
        __syncthreads();
        if (c + 1 < NCH) {
            const float* xg2 = xg + (c + 1) * KC;
            const float* wg2 = wg + (size_t)(c + 1) * KC * NEXP;
            #pragma unroll
            for (int u = 0; u < 4; ++u)
                px[u] = *(const float4*)(xg2 + (size_t)u * 32 * DDIM);
            #pragma unroll
            for (int u = 0; u < 2; ++u)
                pw[u] = *(const float4*)(wg2 + (size_t)u * 16 * NEXP);
        }
        // compute: 128 tok x 64 exp x 32 k per block; 2-k sub-steps
        #pragma unroll
        for (int s2 = 0; s2 < KC / 2; ++s2) {
            float xr[8][2];
            #pragma unroll
            for (int t = 0; t < 8; ++t) {
                float2 v = *(const float2*)&xs[XSWZ(ty * 8 + t, 2 * s2)];
                xr[t][0] = v.x; xr[t][1] = v.y;
            }
            float wr[2][4];
            #pragma unroll
            for (int r = 0; r < 2; ++r)
                *(float4*)wr[r] = *(const float4*)&wsm[(2 * s2 + r) * NEXP + e0];
            #pragma unroll
            for (int r = 0; r < 2; ++r)     // k ascending per acc element
                #pragma unroll
                for (int t = 0; t < 8; ++t)
                    #pragma unroll
                    for (int j = 0; j < 4; ++j)
                        acc[t][j] = fmaf(xr[t][r], wr[r][j], acc[t][j]);
        }
    }

    // store partial logits pws[s][tok][e], coalesced float4
    float* pb = pws + ((size_t)s * NTOK + tok0) * NEXP;
    #pragma unroll
    for (int t = 0; t < 8; ++t)
        *(float4*)&pb[(size_t)(ty * 8 + t) * NEXP + e0] = *(float4*)acc[t];
}

__global__ __launch_bounds__(256) void epilogue(
    const float* __restrict__ pws, const float* __restrict__ bias,
    float* __restrict__ out, float* __restrict__ acc_g)
{
    __shared__ int   f_loc[NEXP];
    __shared__ float p_loc[NEXP];
    __shared__ float z_loc;

    const int tid = threadIdx.x;
    const int tx  = tid & 15;         // expert group: 4tx..4tx+3
    const int tg  = tid >> 4;         // token within block 0..15
    const int e0  = tx * 4;
    const int gt  = blockIdx.x * 16 + tg;

    if (tid < NEXP) { f_loc[tid] = 0; p_loc[tid] = 0.0f; }
    if (tid == 0) z_loc = 0.0f;
    __syncthreads();

    // sum 8 partials in fixed ascending-s order, then + bias
    float l[4];
    {
        const size_t ro = (size_t)gt * NEXP + e0;
        float4 q[KSPLIT];
        #pragma unroll
        for (int s = 0; s < KSPLIT; ++s)
            q[s] = *(const float4*)&pws[(size_t)s * NTOK * NEXP + ro];
        float bb[4];
        *(float4*)bb = *(const float4*)&bias[e0];
        float a0 = q[0].x, a1 = q[0].y, a2 = q[0].z, a3 = q[0].w;
        #pragma unroll
        for (int s = 1; s < KSPLIT; ++s) {
            a0 += q[s].x; a1 += q[s].y; a2 += q[s].z; a3 += q[s].w;
        }
        l[0] = a0 + bb[0]; l[1] = a1 + bb[1]; l[2] = a2 + bb[2]; l[3] = a3 + bb[3];
    }

    // local top-2 (stable: ascending e, strict >)
    float v1 = l[0], v2 = -INFINITY;
    int   i1 = e0,   i2 = 0x7fffffff;
    #pragma unroll
    for (int j = 1; j < 4; ++j) {
        float v = l[j]; int e = e0 + j;
        if (v > v1)      { v2 = v1; i2 = i1; v1 = v; i1 = e; }
        else if (v > v2) { v2 = v;  i2 = e; }
    }
    // merge across the 16 lanes of this token (value desc, idx asc)
    #pragma unroll
    for (int off = 1; off < 16; off <<= 1) {
        float o1 = __shfl_xor(v1, off, 16); int oi1 = __shfl_xor(i1, off, 16);
        float o2 = __shfl_xor(v2, off, 16); int oi2 = __shfl_xor(i2, off, 16);
        if (o1 > v1 || (o1 == v1 && oi1 < i1)) {
            float c = v1; int ci = i1;
            v1 = o1; i1 = oi1;
            if (c > o2 || (c == o2 && ci < oi2)) { v2 = c;  i2 = ci;  }
            else                                 { v2 = o2; i2 = oi2; }
        } else {
            if (o1 > v2 || (o1 == v2 && oi1 < i2)) { v2 = o1; i2 = oi1; }
        }
    }
    const float mx = v1;

    float sden[4], dsum = 0.0f;
    #pragma unroll
    for (int j = 0; j < 4; ++j) { sden[j] = __expf(l[j] - mx); dsum += sden[j]; }
    #pragma unroll
    for (int off = 1; off < 16; off <<= 1) dsum += __shfl_xor(dsum, off, 16);
    const float inv = 1.0f / dsum;

    float p[4], zsum = 0.0f;
    #pragma unroll
    for (int j = 0; j < 4; ++j) { p[j] = sden[j] * inv; zsum += __expf(p[j]); }
    #pragma unroll
    for (int off = 1; off < 16; off <<= 1) zsum += __shfl_xor(zsum, off, 16);

    if (tx == 0) {
        const float s2 = __expf(v2 - mx);      // s1 == 1
        const float ci = 1.0f / (1.0f + s2);
        out[2 * gt]     = (float)i1;
        out[2 * gt + 1] = (float)i2;
        out[2 * NTOK + 2 * gt]     = ci;
        out[2 * NTOK + 2 * gt + 1] = s2 * ci;
        atomicAdd(&f_loc[i1], 1);
    }

    {
        float lse = __logf(zsum);
        float l2  = (tx == 0) ? lse * lse : 0.0f;
        #pragma unroll
        for (int off = 1; off < 64; off <<= 1) l2 += __shfl_xor(l2, off);
        if ((tid & 63) == 0) atomicAdd(&z_loc, l2);
    }

    #pragma unroll
    for (int j = 0; j < 4; ++j) {
        p[j] += __shfl_xor(p[j], 16);
        p[j] += __shfl_xor(p[j], 32);
    }
    if ((tid & 63) < 16) {
        #pragma unroll
        for (int j = 0; j < 4; ++j) atomicAdd(&p_loc[e0 + j], p[j]);
    }

    __syncthreads();
    if (tid < NEXP) {
        atomicAdd(&acc_g[64 + tid], p_loc[tid]);
        if (f_loc[tid]) atomicAdd(&acc_g[tid], (float)f_loc[tid]);
    }
    if (tid == 0) atomicAdd(&acc_g[128], z_loc);
}

__global__ void gate_finalize(const float* __restrict__ acc, float* __restrict__ out) {
    int e = threadIdx.x;  // 64 threads
    float v = acc[e] * acc[64 + e];
    #pragma unroll
    for (int off = 32; off > 0; off >>= 1) v += __shfl_down(v, off);
    if (e == 0) {
        const float NT = (float)NTOK;
        out[2 * NTOK * 2]     = 0.01f * (v / (float)NEXP) / (NT * NT);
        out[2 * NTOK * 2 + 1] = 0.1f * acc[128] / NT;
    }
}

extern "C" void kernel_launch(void* const* d_in, const int* in_sizes, int n_in,
                              void* d_out, int out_size, void* d_ws, size_t ws_size,
                              hipStream_t stream) {
    const float* x    = (const float*)d_in[0];
    const float* W    = (const float*)d_in[1];
    const float* bias = (const float*)d_in[2];
    float* out = (float*)d_out;
    float* acc = (float*)d_ws;
    float* pws = acc + PART_OFF;

    zero_acc<<<1, 256, 0, stream>>>(acc);
    gemm_part<<<KSPLIT * (NTOK / MT), 256, 0, stream>>>(x, W, pws);
    epilogue<<<NTOK / 16, 256, 0, stream>>>(pws, bias, out, acc);
    gate_finalize<<<1, 64, 0, stream>>>(acc, out);
}

// Round 5
// 100.817 us; speedup vs baseline: 2.7029x; 2.7029x over previous
//
#include <hip/hip_runtime.h>
#include <math.h>

#define NTOK 16384
#define DDIM 2048
#define NEXP 64
#define MT   128                 // tokens per stage-1 block
#define KSPLIT 8
#define KRANGE (DDIM / KSPLIT)   // 256
#define KC   16                  // k per LDS chunk
#define NCH  (KRANGE / KC)       // 16

// ws layout (floats): [0..63] f counts, [64..127] P sums, [128] sum lse^2,
// [256 ...] partial logits: [KSPLIT][NTOK][NEXP]
#define PART_OFF 256

// x-tile LDS float index, XOR-swizzled so the 4 ty-quadrant rows read per
// xv instruction land in 4 distinct bank groups. XOR operand is a multiple
// of 4 floats (16B granule) -> float4 alignment preserved.
#define XIDX(row, kf) (((row) << 4) + ((kf) ^ ((((row) >> 3) & 3) << 2)))

__device__ __forceinline__ void gload16(const float* g, const float* lds) {
    __builtin_amdgcn_global_load_lds(
        (const __attribute__((address_space(1))) unsigned int*)g,
        (__attribute__((address_space(3))) unsigned int*)lds, 16, 0, 0);
}

__global__ void zero_acc(float* acc) {
    int t = threadIdx.x;
    if (t < 129) acc[t] = 0.0f;
}

__global__ __launch_bounds__(256, 4) void gemm_part(
    const float* __restrict__ x, const float* __restrict__ W,
    float* __restrict__ pws)
{
    __shared__ __align__(16) float xb[2][MT * KC];   // 2 x 8 KB, swizzled
    __shared__ __align__(16) float wb[2][KC * NEXP]; // 2 x 4 KB, linear

    const int tid  = threadIdx.x;
    const int tb   = blockIdx.x & (NTOK / MT - 1);  // token block 0..127
    const int s    = blockIdx.x >> 7;               // k-split 0..7
    const int tok0 = tb * MT;
    const int kb   = s * KRANGE;

    const int tx = tid & 15;             // experts 4tx..4tx+3
    const int ty = tid >> 4;             // tokens 8ty..8ty+7
    const int e0 = tx * 4;
    const int w  = tid >> 6;             // wave 0..3
    const int l  = tid & 63;             // lane

    // --- staging source addresses (inverse-swizzled: lane reads the global
    // element that belongs at its linear LDS slot) ---
    // x: slot o = u*1024 + w*256 + l*4 ; row=o>>4, col=(o&15)^swz(row)
    const int xo   = w * 256 + l * 4;
    const int xrow = xo >> 4;
    const int xcol = (xo & 15) ^ (((xrow >> 3) & 3) << 2);
    const float* xsrc0 = x + (size_t)(tok0 + xrow) * DDIM + kb + xcol;
    const float* xsrc1 = xsrc0 + (size_t)64 * DDIM;   // u=1: rows +64, same col
    // W: slot o = w*256 + l*4 ; row=o>>6, col=o&63 (linear)
    const int wrow = (w * 256 + l * 4) >> 6;
    const int wcol = (l & 15) * 4;
    const float* wsrc = W + (size_t)(kb + wrow) * NEXP + wcol;

    float accv[8][4];
    #pragma unroll
    for (int t = 0; t < 8; ++t)
        #pragma unroll
        for (int j = 0; j < 4; ++j) accv[t][j] = 0.0f;

    // prologue: stage chunk 0 into buffer 0
    gload16(xsrc0, &xb[0][w * 256]);
    gload16(xsrc1, &xb[0][1024 + w * 256]);
    gload16(wsrc,  &wb[0][w * 256]);

    for (int c = 0; c < NCH; ++c) {
        __syncthreads();   // drains vmcnt -> chunk c staged; prev compute done
        const int cur = c & 1;
        if (c + 1 < NCH) {
            const int nb = cur ^ 1;
            gload16(xsrc0 + (c + 1) * KC, &xb[nb][w * 256]);
            gload16(xsrc1 + (c + 1) * KC, &xb[nb][1024 + w * 256]);
            gload16(wsrc + (size_t)(c + 1) * KC * NEXP, &wb[nb][w * 256]);
        }
        const float* xcb = xb[cur];
        const float* wcb = wb[cur];
        #pragma unroll
        for (int s2 = 0; s2 < KC / 4; ++s2) {
            float wr[4][4];
            #pragma unroll
            for (int r = 0; r < 4; ++r)
                *(float4*)wr[r] = *(const float4*)&wcb[(4 * s2 + r) * NEXP + e0];
            #pragma unroll
            for (int t = 0; t < 8; ++t) {
                float xr[4];
                *(float4*)xr = *(const float4*)&xcb[XIDX(ty * 8 + t, 4 * s2)];
                #pragma unroll
                for (int r = 0; r < 4; ++r)      // k ascending per acc element
                    #pragma unroll
                    for (int j = 0; j < 4; ++j)
                        accv[t][j] = fmaf(xr[r], wr[r][j], accv[t][j]);
            }
        }
    }

    // store partial logits pws[s][tok][e], coalesced float4
    float* pb = pws + ((size_t)s * NTOK + tok0) * NEXP;
    #pragma unroll
    for (int t = 0; t < 8; ++t)
        *(float4*)&pb[(size_t)(ty * 8 + t) * NEXP + e0] = *(float4*)accv[t];
}

__global__ __launch_bounds__(256) void epilogue(
    const float* __restrict__ pws, const float* __restrict__ bias,
    float* __restrict__ out, float* __restrict__ acc_g)
{
    __shared__ int   f_loc[NEXP];
    __shared__ float p_loc[NEXP];
    __shared__ float z_loc;

    const int tid = threadIdx.x;
    const int tx  = tid & 15;         // expert group: 4tx..4tx+3
    const int tg  = tid >> 4;         // token within block 0..15
    const int e0  = tx * 4;
    const int gt  = blockIdx.x * 16 + tg;

    if (tid < NEXP) { f_loc[tid] = 0; p_loc[tid] = 0.0f; }
    if (tid == 0) z_loc = 0.0f;
    __syncthreads();

    // sum 8 partials in fixed ascending-s order, then + bias
    float l[4];
    {
        const size_t ro = (size_t)gt * NEXP + e0;
        float4 q[KSPLIT];
        #pragma unroll
        for (int s = 0; s < KSPLIT; ++s)
            q[s] = *(const float4*)&pws[(size_t)s * NTOK * NEXP + ro];
        float bb[4];
        *(float4*)bb = *(const float4*)&bias[e0];
        float a0 = q[0].x, a1 = q[0].y, a2 = q[0].z, a3 = q[0].w;
        #pragma unroll
        for (int s = 1; s < KSPLIT; ++s) {
            a0 += q[s].x; a1 += q[s].y; a2 += q[s].z; a3 += q[s].w;
        }
        l[0] = a0 + bb[0]; l[1] = a1 + bb[1]; l[2] = a2 + bb[2]; l[3] = a3 + bb[3];
    }

    // local top-2 (stable: ascending e, strict >)
    float v1 = l[0], v2 = -INFINITY;
    int   i1 = e0,   i2 = 0x7fffffff;
    #pragma unroll
    for (int j = 1; j < 4; ++j) {
        float v = l[j]; int e = e0 + j;
        if (v > v1)      { v2 = v1; i2 = i1; v1 = v; i1 = e; }
        else if (v > v2) { v2 = v;  i2 = e; }
    }
    // merge across the 16 lanes of this token (value desc, idx asc)
    #pragma unroll
    for (int off = 1; off < 16; off <<= 1) {
        float o1 = __shfl_xor(v1, off, 16); int oi1 = __shfl_xor(i1, off, 16);
        float o2 = __shfl_xor(v2, off, 16); int oi2 = __shfl_xor(i2, off, 16);
        if (o1 > v1 || (o1 == v1 && oi1 < i1)) {
            float c = v1; int ci = i1;
            v1 = o1; i1 = oi1;
            if (c > o2 || (c == o2 && ci < oi2)) { v2 = c;  i2 = ci;  }
            else                                 { v2 = o2; i2 = oi2; }
        } else {
            if (o1 > v2 || (o1 == v2 && oi1 < i2)) { v2 = o1; i2 = oi1; }
        }
    }
    const float mx = v1;

    float sden[4], dsum = 0.0f;
    #pragma unroll
    for (int j = 0; j < 4; ++j) { sden[j] = __expf(l[j] - mx); dsum += sden[j]; }
    #pragma unroll
    for (int off = 1; off < 16; off <<= 1) dsum += __shfl_xor(dsum, off, 16);
    const float inv = 1.0f / dsum;

    float p[4], zsum = 0.0f;
    #pragma unroll
    for (int j = 0; j < 4; ++j) { p[j] = sden[j] * inv; zsum += __expf(p[j]); }
    #pragma unroll
    for (int off = 1; off < 16; off <<= 1) zsum += __shfl_xor(zsum, off, 16);

    if (tx == 0) {
        const float s2 = __expf(v2 - mx);      // s1 == 1
        const float ci = 1.0f / (1.0f + s2);
        out[2 * gt]     = (float)i1;
        out[2 * gt + 1] = (float)i2;
        out[2 * NTOK + 2 * gt]     = ci;
        out[2 * NTOK + 2 * gt + 1] = s2 * ci;
        atomicAdd(&f_loc[i1], 1);
    }

    {
        float lse = __logf(zsum);
        float l2  = (tx == 0) ? lse * lse : 0.0f;
        #pragma unroll
        for (int off = 1; off < 64; off <<= 1) l2 += __shfl_xor(l2, off);
        if ((tid & 63) == 0) atomicAdd(&z_loc, l2);
    }

    #pragma unroll
    for (int j = 0; j < 4; ++j) {
        p[j] += __shfl_xor(p[j], 16);
        p[j] += __shfl_xor(p[j], 32);
    }
    if ((tid & 63) < 16) {
        #pragma unroll
        for (int j = 0; j < 4; ++j) atomicAdd(&p_loc[e0 + j], p[j]);
    }

    __syncthreads();
    if (tid < NEXP) {
        atomicAdd(&acc_g[64 + tid], p_loc[tid]);
        if (f_loc[tid]) atomicAdd(&acc_g[tid], (float)f_loc[tid]);
    }
    if (tid == 0) atomicAdd(&acc_g[128], z_loc);
}

__global__ void gate_finalize(const float* __restrict__ acc, float* __restrict__ out) {
    int e = threadIdx.x;  // 64 threads
    float v = acc[e] * acc[64 + e];
    #pragma unroll
    for (int off = 32; off > 0; off >>= 1) v += __shfl_down(v, off);
    if (e == 0) {
        const float NT = (float)NTOK;
        out[2 * NTOK * 2]     = 0.01f * (v / (float)NEXP) / (NT * NT);
        out[2 * NTOK * 2 + 1] = 0.1f * acc[128] / NT;
    }
}

extern "C" void kernel_launch(void* const* d_in, const int* in_sizes, int n_in,
                              void* d_out, int out_size, void* d_ws, size_t ws_size,
                              hipStream_t stream) {
    const float* x    = (const float*)d_in[0];
    const float* W    = (const float*)d_in[1];
    const float* bias = (const float*)d_in[2];
    float* out = (float*)d_out;
    float* acc = (float*)d_ws;
    float* pws = acc + PART_OFF;

    zero_acc<<<1, 256, 0, stream>>>(acc);
    gemm_part<<<KSPLIT * (NTOK / MT), 256, 0, stream>>>(x, W, pws);
    epilogue<<<NTOK / 16, 256, 0, stream>>>(pws, bias, out, acc);
    gate_finalize<<<1, 64, 0, stream>>>(acc, out);
}

// Round 6
// 88.836 us; speedup vs baseline: 3.0674x; 1.1349x over previous
//
#include <hip/hip_runtime.h>
#include <math.h>

#define NTOK 16384
#define DDIM 2048
#define NEXP 64
#define MT   64                  // tokens per stage-1 block
#define KSPLIT 4
#define KRANGE (DDIM / KSPLIT)   // 512
#define KC   32                  // k per LDS chunk (128 B rows: full L2 line)
#define NCH  (KRANGE / KC)       // 16

// ws layout (floats): [0..63] f counts, [64..127] P sums, [128] sum lse^2,
// [256 ...] partial logits: [KSPLIT][NTOK][NEXP]
#define PART_OFF 256

// x-tile LDS float index. Row = 32 floats = 128 B = exactly one bank round,
// so banks depend on col only. XOR col by a per-row quad id so the 4 lane
// groups of a wave (rows 16w+4q+t, q=0..3) hit 4 distinct bank quads.
#define XSWZ(row)      ((((row) >> 2) & 3) << 2)
#define XIDX(row, kf)  (((row) << 5) + ((kf) ^ XSWZ(row)))

__device__ __forceinline__ void gload16(const float* g, const float* lds) {
    __builtin_amdgcn_global_load_lds(
        (const __attribute__((address_space(1))) unsigned int*)g,
        (__attribute__((address_space(3))) unsigned int*)lds, 16, 0, 0);
}

__global__ void zero_acc(float* acc) {
    int t = threadIdx.x;
    if (t < 129) acc[t] = 0.0f;
}

__global__ __launch_bounds__(256, 4) void gemm_part(
    const float* __restrict__ x, const float* __restrict__ W,
    float* __restrict__ pws)
{
    __shared__ __align__(16) float xb[2][MT * KC];   // 2 x 8 KB, swizzled
    __shared__ __align__(16) float wb[2][KC * NEXP]; // 2 x 8 KB, linear

    const int tid  = threadIdx.x;
    const int tb   = blockIdx.x & (NTOK / MT - 1);  // token block 0..255
    const int s    = blockIdx.x >> 8;               // k-split 0..3
    const int tok0 = tb * MT;
    const int kb   = s * KRANGE;

    const int tx = tid & 15;             // experts 4tx..4tx+3
    const int ty = tid >> 4;             // tokens 4ty..4ty+3
    const int e0 = tx * 4;
    const int w  = tid >> 6;             // wave 0..3
    const int l  = tid & 63;             // lane

    // --- staging source addresses (inverse-swizzled x; linear W) ---
    // x slot o = u*1024 + w*256 + l*4 : row=o>>5, col_lds=(l&7)*4
    const int xrow0 = w * 8 + (l >> 3);            // + u*32
    const int xcol  = ((l & 7) * 4) ^ XSWZ(xrow0); // swz depends on row>>2; u*32 doesn't change bits 2-3? 
    // NOTE: XSWZ(row) uses bits 2-3 of row; row = u*32 + w*8 + (l>>3): u*32
    // only touches bit 5+, so XSWZ(xrow0 + u*32) == XSWZ(xrow0). Safe.
    const float* xsrc0 = x + (size_t)(tok0 + xrow0) * DDIM + kb + xcol;
    const float* xsrc1 = xsrc0 + (size_t)32 * DDIM;   // u=1
    // W slot o = u*1024 + w*256 + l*4 : row = u*16 + w*4 + (l>>4), col=(l&15)*4
    const int wrow0 = w * 4 + (l >> 4);               // + u*16
    const int wcol  = (l & 15) * 4;
    const float* wsrc0 = W + (size_t)(kb + wrow0) * NEXP + wcol;
    const float* wsrc1 = wsrc0 + (size_t)16 * NEXP;   // u=1

    float accv[4][4];
    #pragma unroll
    for (int t = 0; t < 4; ++t)
        #pragma unroll
        for (int j = 0; j < 4; ++j) accv[t][j] = 0.0f;

    // prologue: stage chunk 0 into buffer 0
    gload16(xsrc0, &xb[0][w * 256]);
    gload16(xsrc1, &xb[0][1024 + w * 256]);
    gload16(wsrc0, &wb[0][w * 256]);
    gload16(wsrc1, &wb[0][1024 + w * 256]);

    const int tr0 = ty * 4;              // first token row of this thread

    for (int c = 0; c < NCH; ++c) {
        __syncthreads();   // drains vmcnt -> chunk c staged; prev compute done
        const int cur = c & 1;
        if (c + 1 < NCH) {
            const int nb = cur ^ 1;
            const int ko = (c + 1) * KC;
            gload16(xsrc0 + ko, &xb[nb][w * 256]);
            gload16(xsrc1 + ko, &xb[nb][1024 + w * 256]);
            gload16(wsrc0 + (size_t)ko * NEXP, &wb[nb][w * 256]);
            gload16(wsrc1 + (size_t)ko * NEXP, &wb[nb][1024 + w * 256]);
        }
        const float* xcb = xb[cur];
        const float* wcb = wb[cur];
        #pragma unroll
        for (int s2 = 0; s2 < KC / 4; ++s2) {
            float wr[4][4];
            #pragma unroll
            for (int r = 0; r < 4; ++r)
                *(float4*)wr[r] = *(const float4*)&wcb[(4 * s2 + r) * NEXP + e0];
            #pragma unroll
            for (int t = 0; t < 4; ++t) {
                float xr[4];
                *(float4*)xr = *(const float4*)&xcb[XIDX(tr0 + t, 4 * s2)];
                #pragma unroll
                for (int r = 0; r < 4; ++r)      // k ascending per acc element
                    #pragma unroll
                    for (int j = 0; j < 4; ++j)
                        accv[t][j] = fmaf(xr[r], wr[r][j], accv[t][j]);
            }
        }
    }

    // store partial logits pws[s][tok][e], coalesced float4
    float* pb = pws + ((size_t)s * NTOK + tok0) * NEXP;
    #pragma unroll
    for (int t = 0; t < 4; ++t)
        *(float4*)&pb[(size_t)(tr0 + t) * NEXP + e0] = *(float4*)accv[t];
}

#define ETOK 64   // tokens per epilogue block

__global__ __launch_bounds__(256) void epilogue(
    const float* __restrict__ pws, const float* __restrict__ bias,
    float* __restrict__ out, float* __restrict__ acc_g)
{
    __shared__ int   f_loc[NEXP];
    __shared__ float p_loc[NEXP];
    __shared__ float z_loc;

    const int tid = threadIdx.x;
    const int tx  = tid & 15;         // expert group: 4tx..4tx+3
    const int tg  = tid >> 4;         // token slot 0..15
    const int e0  = tx * 4;

    if (tid < NEXP) { f_loc[tid] = 0; p_loc[tid] = 0.0f; }
    if (tid == 0) z_loc = 0.0f;
    __syncthreads();

    float bb[4];
    *(float4*)bb = *(const float4*)&bias[e0];

    float pacc[4] = {0.f, 0.f, 0.f, 0.f};
    float zacc = 0.0f;

    for (int it = 0; it < ETOK / 16; ++it) {
        const int gt = blockIdx.x * ETOK + it * 16 + tg;

        // sum 4 partials in fixed ascending-s order, then + bias
        float l[4];
        {
            const size_t ro = (size_t)gt * NEXP + e0;
            float4 q0 = *(const float4*)&pws[ro];
            float4 q1 = *(const float4*)&pws[(size_t)1 * NTOK * NEXP + ro];
            float4 q2 = *(const float4*)&pws[(size_t)2 * NTOK * NEXP + ro];
            float4 q3 = *(const float4*)&pws[(size_t)3 * NTOK * NEXP + ro];
            l[0] = ((q0.x + q1.x) + q2.x) + q3.x + bb[0];
            l[1] = ((q0.y + q1.y) + q2.y) + q3.y + bb[1];
            l[2] = ((q0.z + q1.z) + q2.z) + q3.z + bb[2];
            l[3] = ((q0.w + q1.w) + q2.w) + q3.w + bb[3];
        }

        // local top-2 (stable: ascending e, strict >)
        float v1 = l[0], v2 = -INFINITY;
        int   i1 = e0,   i2 = 0x7fffffff;
        #pragma unroll
        for (int j = 1; j < 4; ++j) {
            float v = l[j]; int e = e0 + j;
            if (v > v1)      { v2 = v1; i2 = i1; v1 = v; i1 = e; }
            else if (v > v2) { v2 = v;  i2 = e; }
        }
        // merge across the 16 lanes of this token (value desc, idx asc)
        #pragma unroll
        for (int off = 1; off < 16; off <<= 1) {
            float o1 = __shfl_xor(v1, off, 16); int oi1 = __shfl_xor(i1, off, 16);
            float o2 = __shfl_xor(v2, off, 16); int oi2 = __shfl_xor(i2, off, 16);
            if (o1 > v1 || (o1 == v1 && oi1 < i1)) {
                float cs = v1; int ci = i1;
                v1 = o1; i1 = oi1;
                if (cs > o2 || (cs == o2 && ci < oi2)) { v2 = cs; i2 = ci;  }
                else                                   { v2 = o2; i2 = oi2; }
            } else {
                if (o1 > v2 || (o1 == v2 && oi1 < i2)) { v2 = o1; i2 = oi1; }
            }
        }
        const float mx = v1;

        float sden[4], dsum = 0.0f;
        #pragma unroll
        for (int j = 0; j < 4; ++j) { sden[j] = __expf(l[j] - mx); dsum += sden[j]; }
        #pragma unroll
        for (int off = 1; off < 16; off <<= 1) dsum += __shfl_xor(dsum, off, 16);
        const float inv = 1.0f / dsum;

        float zsum = 0.0f;
        #pragma unroll
        for (int j = 0; j < 4; ++j) {
            float pj = sden[j] * inv;
            pacc[j] += pj;
            zsum += __expf(pj);
        }
        #pragma unroll
        for (int off = 1; off < 16; off <<= 1) zsum += __shfl_xor(zsum, off, 16);

        if (tx == 0) {
            const float s2 = __expf(v2 - mx);      // s1 == 1
            const float ci = 1.0f / (1.0f + s2);
            out[2 * gt]     = (float)i1;
            out[2 * gt + 1] = (float)i2;
            out[2 * NTOK + 2 * gt]     = ci;
            out[2 * NTOK + 2 * gt + 1] = s2 * ci;
            atomicAdd(&f_loc[i1], 1);
            float lse = __logf(zsum);
            zacc += lse * lse;
        }
    }

    // z: wave-reduce (only tx==0 lanes carry nonzero), one LDS atomic per wave
    #pragma unroll
    for (int off = 1; off < 64; off <<= 1) zacc += __shfl_xor(zacc, off);
    if ((tid & 63) == 0) atomicAdd(&z_loc, zacc);

    // P: fold token-groups within wave, then LDS
    #pragma unroll
    for (int j = 0; j < 4; ++j) {
        pacc[j] += __shfl_xor(pacc[j], 16);
        pacc[j] += __shfl_xor(pacc[j], 32);
    }
    if ((tid & 63) < 16) {
        #pragma unroll
        for (int j = 0; j < 4; ++j) atomicAdd(&p_loc[e0 + j], pacc[j]);
    }

    __syncthreads();
    if (tid < NEXP) {
        atomicAdd(&acc_g[64 + tid], p_loc[tid]);
        if (f_loc[tid]) atomicAdd(&acc_g[tid], (float)f_loc[tid]);
    }
    if (tid == 0) atomicAdd(&acc_g[128], z_loc);
}

__global__ void gate_finalize(const float* __restrict__ acc, float* __restrict__ out) {
    int e = threadIdx.x;  // 64 threads
    float v = acc[e] * acc[64 + e];
    #pragma unroll
    for (int off = 32; off > 0; off >>= 1) v += __shfl_down(v, off);
    if (e == 0) {
        const float NT = (float)NTOK;
        out[2 * NTOK * 2]     = 0.01f * (v / (float)NEXP) / (NT * NT);
        out[2 * NTOK * 2 + 1] = 0.1f * acc[128] / NT;
    }
}

extern "C" void kernel_launch(void* const* d_in, const int* in_sizes, int n_in,
                              void* d_out, int out_size, void* d_ws, size_t ws_size,
                              hipStream_t stream) {
    const float* x    = (const float*)d_in[0];
    const float* W    = (const float*)d_in[1];
    const float* bias = (const float*)d_in[2];
    float* out = (float*)d_out;
    float* acc = (float*)d_ws;
    float* pws = acc + PART_OFF;

    zero_acc<<<1, 256, 0, stream>>>(acc);
    gemm_part<<<KSPLIT * (NTOK / MT), 256, 0, stream>>>(x, W, pws);
    epilogue<<<NTOK / ETOK, 256, 0, stream>>>(pws, bias, out, acc);
    gate_finalize<<<1, 64, 0, stream>>>(acc, out);
}